// Round 5
// baseline (1073.338 us; speedup 1.0000x reference)
//
#include <hip/hip_runtime.h>

#define EPS 1e-15f

// ---------- in-degree histogram (int counts) ----------
__global__ void k_hist(const int* __restrict__ ei, int E, int* __restrict__ counts) {
    int e = blockIdx.x * blockDim.x + threadIdx.x;
    if (e < E) atomicAdd(&counts[ei[E + e]], 1);
}

// ---------- single-block exclusive scan -> off/cursor; also isd ----------
__global__ __launch_bounds__(1024) void k_scan(const int* __restrict__ counts,
                                               int* __restrict__ off,
                                               int* __restrict__ cursor,
                                               float* __restrict__ isd, int n) {
    __shared__ int part[1024];
    const int tid = threadIdx.x;
    const int per = (n + 1023) >> 10;
    const int lo = min(tid * per, n);
    const int hi = min(lo + per, n);
    int s = 0;
    for (int i = lo; i < hi; ++i) s += counts[i];
    part[tid] = s;
    __syncthreads();
    for (int d = 1; d < 1024; d <<= 1) {          // Hillis-Steele inclusive scan
        int v = (tid >= d) ? part[tid - d] : 0;
        __syncthreads();
        part[tid] += v;
        __syncthreads();
    }
    int run = part[tid] - s;                       // exclusive prefix for this chunk
    for (int i = lo; i < hi; ++i) {
        int c = counts[i];
        off[i] = run;
        cursor[i] = run;
        isd[i] = rsqrtf((float)(c > 1 ? c : 1));
        run += c;
    }
    if (tid == 1023) off[n] = run;
}

// ---------- scatter edges into dst-sorted CSR (store src) ----------
__global__ void k_fill(const int* __restrict__ ei, int E,
                       int* __restrict__ cursor, int* __restrict__ csr) {
    int e = blockIdx.x * blockDim.x + threadIdx.x;
    if (e < E) {
        int dst = ei[E + e];
        int slot = atomicAdd(&cursor[dst], 1);
        csr[slot] = ei[e];
    }
}

// ---------- per-dst register aggregation of raw x ----------
// wave = dst node, lane = x-feature. h[n, k*64+i] = (1/deg) * sum_e gw_k * x[src_e, i]
__global__ __launch_bounds__(256) void k_gather(const int* __restrict__ off,
                                                const int* __restrict__ csr,
                                                const float* __restrict__ isd,
                                                const float* __restrict__ x,
                                                const float* __restrict__ mu,
                                                const float* __restrict__ sigma,
                                                float* __restrict__ h, int n) {
    const int lane = threadIdx.x & 63;
    const int wid  = (blockIdx.x * blockDim.x + threadIdx.x) >> 6;
    const int nw   = (gridDim.x * blockDim.x) >> 6;
    float mu0[4], w0[4], mu1[4], w1[4];
    #pragma unroll
    for (int k = 0; k < 4; ++k) {
        mu0[k] = mu[2 * k];
        mu1[k] = mu[2 * k + 1];
        float s0 = sigma[2 * k], s1 = sigma[2 * k + 1];
        w0[k] = -0.5f / (EPS + s0 * s0);
        w1[k] = -0.5f / (EPS + s1 * s1);
    }
    for (int node = wid; node < n; node += nw) {
        const int base = off[node];
        const int len  = off[node + 1] - base;
        const float idd = isd[node];
        float e1[4];
        #pragma unroll
        for (int k = 0; k < 4; ++k) { float d = idd - mu1[k]; e1[k] = d * d * w1[k]; }
        float a0 = 0.f, a1 = 0.f, a2 = 0.f, a3 = 0.f;
        for (int j = 0; j < len; ++j) {
            int s = csr[base + j];                     // wave-uniform (HW broadcast)
            float iss = isd[s];                        // wave-uniform
            float xv = x[(size_t)s * 64 + lane];       // 256B coalesced, cache-resident
            float d0 = iss - mu0[0]; float g0 = __expf(d0 * d0 * w0[0] + e1[0]);
            float d1 = iss - mu0[1]; float g1 = __expf(d1 * d1 * w0[1] + e1[1]);
            float d2 = iss - mu0[2]; float g2 = __expf(d2 * d2 * w0[2] + e1[2]);
            float d3 = iss - mu0[3]; float g3 = __expf(d3 * d3 * w0[3] + e1[3]);
            a0 += g0 * xv; a1 += g1 * xv; a2 += g2 * xv; a3 += g3 * xv;
        }
        const float invd = 1.0f / (float)(len > 1 ? len : 1);
        size_t hb = (size_t)node * 256;
        h[hb + lane]        = a0 * invd;
        h[hb + 64 + lane]   = a1 * invd;
        h[hb + 128 + lane]  = a2 * invd;
        h[hb + 192 + lane]  = a3 * invd;
    }
}

// ---------- p = h @ G'   (G'[k*64+i][j] = g[i][k*64+j], staged in LDS 64KB) ----------
// block = 1024 (16 waves), wave handles 16 nodes, lane = output col j.
__global__ __launch_bounds__(1024, 4) void k_tx1(const float* __restrict__ h,
                                                 const float* __restrict__ g,
                                                 float* __restrict__ p, int n) {
    __shared__ float B[256 * 64];
    for (int t = threadIdx.x; t < 256 * 64 / 4; t += 1024) {
        int c = (4 * t) >> 6;
        int j = (4 * t) & 63;
        int k = c >> 6, i = c & 63;
        *reinterpret_cast<float4*>(&B[4 * t]) =
            *reinterpret_cast<const float4*>(&g[i * 256 + k * 64 + j]);
    }
    __syncthreads();
    const int lane = threadIdx.x & 63;
    const int w    = __builtin_amdgcn_readfirstlane(threadIdx.x >> 6);
    const int ntile = (n + 15) >> 4;
    for (int tile = blockIdx.x * 16 + w; tile < ntile; tile += gridDim.x * 16) {
        const int r0 = tile * 16;
        const int rmax = min(16, n - r0);
        float acc[16];
        #pragma unroll
        for (int r = 0; r < 16; ++r) acc[r] = 0.f;
        if (rmax == 16) {
            for (int c = 0; c < 256; c += 4) {
                float b0 = B[c * 64 + lane],     b1 = B[(c + 1) * 64 + lane];
                float b2 = B[(c + 2) * 64 + lane], b3 = B[(c + 3) * 64 + lane];
                #pragma unroll
                for (int r = 0; r < 16; ++r) {
                    float4 hv = *reinterpret_cast<const float4*>(&h[(size_t)(r0 + r) * 256 + c]);
                    acc[r] += hv.x * b0 + hv.y * b1 + hv.z * b2 + hv.w * b3;
                }
            }
            #pragma unroll
            for (int r = 0; r < 16; ++r) p[(size_t)(r0 + r) * 64 + lane] = acc[r];
        } else {
            for (int c = 0; c < 256; c += 4) {
                float b0 = B[c * 64 + lane],     b1 = B[(c + 1) * 64 + lane];
                float b2 = B[(c + 2) * 64 + lane], b3 = B[(c + 3) * 64 + lane];
                #pragma unroll
                for (int r = 0; r < 16; ++r) {
                    if (r < rmax) {
                        float4 hv = *reinterpret_cast<const float4*>(&h[(size_t)(r0 + r) * 256 + c]);
                        acc[r] += hv.x * b0 + hv.y * b1 + hv.z * b2 + hv.w * b3;
                    }
                }
            }
            #pragma unroll
            for (int r = 0; r < 16; ++r)
                if (r < rmax) p[(size_t)(r0 + r) * 64 + lane] = acc[r];
        }
    }
}

// ---------- out = x + relu(p + x@root + bias)  (p aliases out buffer) ----------
__global__ __launch_bounds__(1024, 4) void k_tx2(const float* __restrict__ x,
                                                 const float* __restrict__ root,
                                                 const float* __restrict__ bias,
                                                 float* po, int n) {
    __shared__ float R[64 * 64];
    __shared__ float bs[64];
    for (int t = threadIdx.x; t < 64 * 64 / 4; t += 1024)
        *reinterpret_cast<float4*>(&R[4 * t]) =
            *reinterpret_cast<const float4*>(&root[4 * t]);
    if (threadIdx.x < 16)
        reinterpret_cast<float4*>(bs)[threadIdx.x] =
            reinterpret_cast<const float4*>(bias)[threadIdx.x];
    __syncthreads();
    const int lane = threadIdx.x & 63;
    const int w    = __builtin_amdgcn_readfirstlane(threadIdx.x >> 6);
    const int ntile = (n + 15) >> 4;
    for (int tile = blockIdx.x * 16 + w; tile < ntile; tile += gridDim.x * 16) {
        const int r0 = tile * 16;
        const int rmax = min(16, n - r0);
        float acc[16];
        #pragma unroll
        for (int r = 0; r < 16; ++r) acc[r] = bs[lane];
        if (rmax == 16) {
            for (int c = 0; c < 64; c += 4) {
                float b0 = R[c * 64 + lane],     b1 = R[(c + 1) * 64 + lane];
                float b2 = R[(c + 2) * 64 + lane], b3 = R[(c + 3) * 64 + lane];
                #pragma unroll
                for (int r = 0; r < 16; ++r) {
                    float4 xv = *reinterpret_cast<const float4*>(&x[(size_t)(r0 + r) * 64 + c]);
                    acc[r] += xv.x * b0 + xv.y * b1 + xv.z * b2 + xv.w * b3;
                }
            }
            #pragma unroll
            for (int r = 0; r < 16; ++r) {
                size_t o = (size_t)(r0 + r) * 64 + lane;
                float xres = x[o];
                float conv = acc[r] + po[o];
                po[o] = xres + (conv > 0.f ? conv : 0.f);
            }
        } else {
            for (int c = 0; c < 64; c += 4) {
                float b0 = R[c * 64 + lane],     b1 = R[(c + 1) * 64 + lane];
                float b2 = R[(c + 2) * 64 + lane], b3 = R[(c + 3) * 64 + lane];
                #pragma unroll
                for (int r = 0; r < 16; ++r) {
                    if (r < rmax) {
                        float4 xv = *reinterpret_cast<const float4*>(&x[(size_t)(r0 + r) * 64 + c]);
                        acc[r] += xv.x * b0 + xv.y * b1 + xv.z * b2 + xv.w * b3;
                    }
                }
            }
            #pragma unroll
            for (int r = 0; r < 16; ++r) {
                if (r < rmax) {
                    size_t o = (size_t)(r0 + r) * 64 + lane;
                    float xres = x[o];
                    float conv = acc[r] + po[o];
                    po[o] = xres + (conv > 0.f ? conv : 0.f);
                }
            }
        }
    }
}

extern "C" void kernel_launch(void* const* d_in, const int* in_sizes, int n_in,
                              void* d_out, int out_size, void* d_ws, size_t ws_size,
                              hipStream_t stream) {
    const float* x     = (const float*)d_in[0];
    const int*   ei    = (const int*)d_in[1];
    const float* g     = (const float*)d_in[2];
    const float* mu    = (const float*)d_in[3];
    const float* sigma = (const float*)d_in[4];
    const float* root  = (const float*)d_in[5];
    const float* bias  = (const float*)d_in[6];
    float* out = (float*)d_out;

    const int n = in_sizes[0] / 64;   // 100000
    const int E = in_sizes[1] / 2;    // 1600000

    // ws layout (4B units): counts[n] | off[n+4] | cursor[n] | isd[n] | csr[E] | h[n*256]
    // h offset = 4n+4+E floats -> 8,000,016 B, 16B-aligned for float4.  Total ≈ 110.4 MB.
    int*   counts = (int*)d_ws;
    int*   off    = counts + n;
    int*   cursor = off + n + 4;
    float* isd    = (float*)(cursor + n);
    int*   csr    = (int*)(isd + n);
    float* h      = (float*)(csr + E);

    hipMemsetAsync(counts, 0, (size_t)n * sizeof(int), stream);

    k_hist<<<(E + 255) / 256, 256, 0, stream>>>(ei, E, counts);
    k_scan<<<1, 1024, 0, stream>>>(counts, off, cursor, isd, n);
    k_fill<<<(E + 255) / 256, 256, 0, stream>>>(ei, E, cursor, csr);
    k_gather<<<2048, 256, 0, stream>>>(off, csr, isd, x, mu, sigma, h, n);
    k_tx1<<<256, 1024, 0, stream>>>(h, g, out, n);
    k_tx2<<<256, 1024, 0, stream>>>(x, root, bias, out, n);
}

// Round 7
// 868.841 us; speedup vs baseline: 1.2354x; 1.2354x over previous
//
#include <hip/hip_runtime.h>

#define EPS 1e-15f

__device__ __forceinline__ float rl(float v, int l) {
    return __int_as_float(__builtin_amdgcn_readlane(__float_as_int(v), l));
}

// ---------- in-degree histogram (int counts) ----------
__global__ void k_hist(const int* __restrict__ ei, int E, int* __restrict__ counts) {
    int e = blockIdx.x * blockDim.x + threadIdx.x;
    if (e < E) atomicAdd(&counts[ei[E + e]], 1);
}

// ---------- single-block exclusive scan -> off/cursor; also isd ----------
__global__ __launch_bounds__(1024) void k_scan(const int* __restrict__ counts,
                                               int* __restrict__ off,
                                               int* __restrict__ cursor,
                                               float* __restrict__ isd, int n) {
    __shared__ int part[1024];
    const int tid = threadIdx.x;
    const int per = (n + 1023) >> 10;
    const int lo = min(tid * per, n);
    const int hi = min(lo + per, n);
    int s = 0;
    for (int i = lo; i < hi; ++i) s += counts[i];
    part[tid] = s;
    __syncthreads();
    for (int d = 1; d < 1024; d <<= 1) {          // Hillis-Steele inclusive scan
        int v = (tid >= d) ? part[tid - d] : 0;
        __syncthreads();
        part[tid] += v;
        __syncthreads();
    }
    int run = part[tid] - s;                       // exclusive prefix for this chunk
    for (int i = lo; i < hi; ++i) {
        int c = counts[i];
        off[i] = run;
        cursor[i] = run;
        isd[i] = rsqrtf((float)(c > 1 ? c : 1));
        run += c;
    }
    if (tid == 1023) off[n] = run;
}

// ---------- scatter edges into dst-sorted CSR (store src) ----------
__global__ void k_fill(const int* __restrict__ ei, int E,
                       int* __restrict__ cursor, int* __restrict__ csr) {
    int e = blockIdx.x * blockDim.x + threadIdx.x;
    if (e < E) {
        int dst = ei[E + e];
        int slot = atomicAdd(&cursor[dst], 1);
        csr[slot] = ei[e];
    }
}

// ---------- per-dst register aggregation of raw x (depth-2 pipelined) ----------
// wave = dst node, lane = x-feature. h[n, k*64+i] = (1/deg) * sum_e gw_k * x[src_e, i]
__global__ __launch_bounds__(256) void k_gather(const int* __restrict__ off,
                                                const int* __restrict__ csr,
                                                const float* __restrict__ isd,
                                                const float* __restrict__ x,
                                                const float* __restrict__ mu,
                                                const float* __restrict__ sigma,
                                                float* __restrict__ h, int n) {
    const int lane = threadIdx.x & 63;
    const int wid  = (blockIdx.x * blockDim.x + threadIdx.x) >> 6;
    const int nw   = (gridDim.x * blockDim.x) >> 6;
    float mu0[4], w0[4], mu1[4], w1[4];
    #pragma unroll
    for (int k = 0; k < 4; ++k) {
        mu0[k] = mu[2 * k];
        mu1[k] = mu[2 * k + 1];
        float s0 = sigma[2 * k], s1 = sigma[2 * k + 1];
        w0[k] = -0.5f / (EPS + s0 * s0);
        w1[k] = -0.5f / (EPS + s1 * s1);
    }
    for (int node = wid; node < n; node += nw) {
        const int base = off[node];
        const int len  = off[node + 1] - base;
        const float idd = isd[node];
        float e1[4];
        #pragma unroll
        for (int k = 0; k < 4; ++k) { float d = idd - mu1[k]; e1[k] = d * d * w1[k]; }
        float a0 = 0.f, a1 = 0.f, a2 = 0.f, a3 = 0.f;
        if (len > 0) {
            // software pipeline: index 2 ahead, data 1 ahead
            int   s_cur  = csr[base];
            float is_cur = isd[s_cur];
            float xv_cur = x[(size_t)s_cur * 64 + lane];
            int   s_nxt  = (len > 1) ? csr[base + 1] : s_cur;
            for (int j = 0; j < len; ++j) {
                int   s_n2  = (j + 2 < len) ? csr[base + j + 2] : s_nxt;
                float is_n  = isd[s_nxt];
                float xv_n  = x[(size_t)s_nxt * 64 + lane];
                float d0 = is_cur - mu0[0]; float g0 = __expf(d0 * d0 * w0[0] + e1[0]);
                float d1 = is_cur - mu0[1]; float g1 = __expf(d1 * d1 * w0[1] + e1[1]);
                float d2 = is_cur - mu0[2]; float g2 = __expf(d2 * d2 * w0[2] + e1[2]);
                float d3 = is_cur - mu0[3]; float g3 = __expf(d3 * d3 * w0[3] + e1[3]);
                a0 += g0 * xv_cur; a1 += g1 * xv_cur;
                a2 += g2 * xv_cur; a3 += g3 * xv_cur;
                is_cur = is_n; xv_cur = xv_n; s_nxt = s_n2;
            }
        }
        const float invd = 1.0f / (float)(len > 1 ? len : 1);
        size_t hb = (size_t)node * 256;
        h[hb + lane]        = a0 * invd;
        h[hb + 64 + lane]   = a1 * invd;
        h[hb + 128 + lane]  = a2 * invd;
        h[hb + 192 + lane]  = a3 * invd;
    }
}

// ---------- fused transform: out = x + relu(h@B + x@root + bias) ----------
// B[c][j] = g[c&63][(c>>6)*64 + j] staged in LDS (64 KB exactly).
// Wave tile = 16 rows; lane = output col j. h/x loads are lane-varying
// coalesced; the per-element h[r][c] broadcast uses v_readlane (VALU pipe).
__global__ __launch_bounds__(256, 2) void k_tx(const float* __restrict__ h,
                                               const float* __restrict__ x,
                                               const float* __restrict__ g,
                                               const float* __restrict__ root,
                                               const float* __restrict__ bias,
                                               float* __restrict__ out, int n) {
    __shared__ float Bs[256 * 64];
    for (int t = threadIdx.x; t < 4096; t += 256) {
        int idx = t * 4;
        int c = idx >> 6;
        int j = idx & 63;                  // multiple of 4
        int k = c >> 6, i = c & 63;
        *reinterpret_cast<float4*>(&Bs[idx]) =
            *reinterpret_cast<const float4*>(&g[i * 256 + k * 64 + j]);
    }
    __syncthreads();

    const int lane  = threadIdx.x & 63;
    const int w     = __builtin_amdgcn_readfirstlane(threadIdx.x >> 6);
    const int ntile = (n + 15) >> 4;
    const float bias_v = bias[lane];

    for (int tile = blockIdx.x * 4 + w; tile < ntile; tile += gridDim.x * 4) {
        const int r0 = tile * 16;
        float hvA[16], hvB[16], xv[16], acc[16];

        #pragma unroll
        for (int r = 0; r < 16; ++r) {
            int row = r0 + r; row = row < n ? row : n - 1;
            xv[r]  = x[(size_t)row * 64 + lane];
            hvA[r] = h[(size_t)row * 256 + lane];          // seg 0
            acc[r] = bias_v;
        }

        #pragma unroll
        for (int seg = 0; seg < 4; ++seg) {
            float (&cur)[16] = (seg & 1) ? hvB : hvA;
            float (&nxt)[16] = (seg & 1) ? hvA : hvB;
            if (seg < 3) {
                #pragma unroll
                for (int r = 0; r < 16; ++r) {
                    int row = r0 + r; row = row < n ? row : n - 1;
                    nxt[r] = h[(size_t)row * 256 + (seg + 1) * 64 + lane];
                }
            }
            const float* Brow = &Bs[seg * 64 * 64];
            for (int dd = 0; dd < 64; ++dd) {
                float bB = Brow[dd * 64 + lane];           // stride-1 over lanes
                #pragma unroll
                for (int r = 0; r < 16; ++r)
                    acc[r] = fmaf(rl(cur[r], dd), bB, acc[r]);
            }
        }

        // x @ root part: root row dd is 256B, 16KB total -> L1-resident
        for (int dd = 0; dd < 64; ++dd) {
            float rv = root[dd * 64 + lane];
            #pragma unroll
            for (int r = 0; r < 16; ++r)
                acc[r] = fmaf(rl(xv[r], dd), rv, acc[r]);
        }

        #pragma unroll
        for (int r = 0; r < 16; ++r) {
            int row = r0 + r;
            if (row < n) {
                float conv = acc[r];
                out[(size_t)row * 64 + lane] = xv[r] + (conv > 0.f ? conv : 0.f);
            }
        }
    }
}

extern "C" void kernel_launch(void* const* d_in, const int* in_sizes, int n_in,
                              void* d_out, int out_size, void* d_ws, size_t ws_size,
                              hipStream_t stream) {
    const float* x     = (const float*)d_in[0];
    const int*   ei    = (const int*)d_in[1];
    const float* g     = (const float*)d_in[2];
    const float* mu    = (const float*)d_in[3];
    const float* sigma = (const float*)d_in[4];
    const float* root  = (const float*)d_in[5];
    const float* bias  = (const float*)d_in[6];
    float* out = (float*)d_out;

    const int n = in_sizes[0] / 64;   // 100000
    const int E = in_sizes[1] / 2;    // 1600000

    // ws layout (4B units): counts[n] | off[n+4] | cursor[n] | isd[n] | csr[E] | h[n*256]
    // h offset = 4n+4+E floats -> 8,000,016 B, 16B-aligned for float4.  Total ≈ 110.4 MB.
    int*   counts = (int*)d_ws;
    int*   off    = counts + n;
    int*   cursor = off + n + 4;
    float* isd    = (float*)(cursor + n);
    int*   csr    = (int*)(isd + n);
    float* h      = (float*)(csr + E);

    hipMemsetAsync(counts, 0, (size_t)n * sizeof(int), stream);

    k_hist<<<(E + 255) / 256, 256, 0, stream>>>(ei, E, counts);
    k_scan<<<1, 1024, 0, stream>>>(counts, off, cursor, isd, n);
    k_fill<<<(E + 255) / 256, 256, 0, stream>>>(ei, E, cursor, csr);
    k_gather<<<2048, 256, 0, stream>>>(off, csr, isd, x, mu, sigma, h, n);
    k_tx<<<512, 256, 0, stream>>>(h, x, g, root, bias, out, n);
}

// Round 8
// 588.508 us; speedup vs baseline: 1.8238x; 1.4763x over previous
//
#include <hip/hip_runtime.h>

#define EPS 1e-15f

__device__ __forceinline__ float rl(float v, int l) {
    return __int_as_float(__builtin_amdgcn_readlane(__float_as_int(v), l));
}

// ---------- in-degree histogram (int counts) ----------
__global__ void k_hist(const int* __restrict__ ei, int E, int* __restrict__ counts) {
    int e = blockIdx.x * blockDim.x + threadIdx.x;
    if (e < E) atomicAdd(&counts[ei[E + e]], 1);
}

// ---------- parallel scan, phase 1: per-block sums (1024 elems/block) ----------
__global__ __launch_bounds__(1024) void k_scan1(const int* __restrict__ counts, int n,
                                                int* __restrict__ bsum) {
    int i = blockIdx.x * 1024 + threadIdx.x;
    int v = (i < n) ? counts[i] : 0;
    #pragma unroll
    for (int d = 1; d < 64; d <<= 1) v += __shfl_xor(v, d);
    __shared__ int wsum[16];
    if ((threadIdx.x & 63) == 0) wsum[threadIdx.x >> 6] = v;
    __syncthreads();
    if (threadIdx.x < 16) {
        int s = wsum[threadIdx.x];
        #pragma unroll
        for (int d = 1; d < 16; d <<= 1) s += __shfl_xor(s, d, 16);
        if (threadIdx.x == 0) bsum[blockIdx.x] = s;
    }
}

// ---------- phase 2: exclusive scan of block sums (1 tiny block) ----------
__global__ __launch_bounds__(1024) void k_scan2(const int* __restrict__ bsum,
                                                int* __restrict__ bpre, int nb) {
    __shared__ int sh[1024];
    int t = threadIdx.x;
    int v = (t < nb) ? bsum[t] : 0;
    sh[t] = v;
    __syncthreads();
    for (int d = 1; d < 1024; d <<= 1) {
        int u = (t >= d) ? sh[t - d] : 0;
        __syncthreads();
        sh[t] += u;
        __syncthreads();
    }
    if (t < nb) bpre[t] = sh[t] - v;   // exclusive prefix
}

// ---------- phase 3: intra-block exclusive scan + write off/cursor/isd ----------
__global__ __launch_bounds__(1024) void k_scan3(const int* __restrict__ counts,
                                                const int* __restrict__ bpre,
                                                int* __restrict__ off,
                                                int* __restrict__ cursor,
                                                float* __restrict__ isd, int n) {
    __shared__ int woff[17];
    int i = blockIdx.x * 1024 + threadIdx.x;
    int lane = threadIdx.x & 63;
    int wv = threadIdx.x >> 6;
    int c = (i < n) ? counts[i] : 0;
    int v = c;
    #pragma unroll
    for (int d = 1; d < 64; d <<= 1) {      // intra-wave inclusive scan
        int u = __shfl_up(v, d);
        if (lane >= d) v += u;
    }
    if (lane == 63) woff[wv + 1] = v;        // wave totals
    if (threadIdx.x == 0) woff[0] = 0;
    __syncthreads();
    if (threadIdx.x == 0) {
        #pragma unroll
        for (int k = 1; k < 16; ++k) woff[k + 1] += woff[k];
    }
    __syncthreads();
    if (i < n) {
        int excl = v - c + woff[wv] + bpre[blockIdx.x];
        off[i] = excl;
        cursor[i] = excl;
        isd[i] = rsqrtf((float)(c > 1 ? c : 1));
        if (i == n - 1) off[n] = excl + c;
    }
}

// ---------- scatter edges into dst-sorted CSR (store src) ----------
__global__ void k_fill(const int* __restrict__ ei, int E,
                       int* __restrict__ cursor, int* __restrict__ csr) {
    int e = blockIdx.x * blockDim.x + threadIdx.x;
    if (e < E) {
        int dst = ei[E + e];
        int slot = atomicAdd(&cursor[dst], 1);
        csr[slot] = ei[e];
    }
}

// ---------- per-dst register aggregation of raw x (depth-2 pipelined) ----------
// wave = dst node, lane = x-feature. h[n, k*64+i] = (1/deg) * sum_e gw_k * x[src_e, i]
__global__ __launch_bounds__(256) void k_gather(const int* __restrict__ off,
                                                const int* __restrict__ csr,
                                                const float* __restrict__ isd,
                                                const float* __restrict__ x,
                                                const float* __restrict__ mu,
                                                const float* __restrict__ sigma,
                                                float* __restrict__ h, int n) {
    const int lane = threadIdx.x & 63;
    const int wid  = (blockIdx.x * blockDim.x + threadIdx.x) >> 6;
    const int nw   = (gridDim.x * blockDim.x) >> 6;
    float mu0[4], w0[4], mu1[4], w1[4];
    #pragma unroll
    for (int k = 0; k < 4; ++k) {
        mu0[k] = mu[2 * k];
        mu1[k] = mu[2 * k + 1];
        float s0 = sigma[2 * k], s1 = sigma[2 * k + 1];
        w0[k] = -0.5f / (EPS + s0 * s0);
        w1[k] = -0.5f / (EPS + s1 * s1);
    }
    for (int node = wid; node < n; node += nw) {
        const int base = off[node];
        const int len  = off[node + 1] - base;
        const float idd = isd[node];
        float e1[4];
        #pragma unroll
        for (int k = 0; k < 4; ++k) { float d = idd - mu1[k]; e1[k] = d * d * w1[k]; }
        float a0 = 0.f, a1 = 0.f, a2 = 0.f, a3 = 0.f;
        if (len > 0) {
            // software pipeline: index 2 ahead, data 1 ahead
            int   s_cur  = csr[base];
            float is_cur = isd[s_cur];
            float xv_cur = x[(size_t)s_cur * 64 + lane];
            int   s_nxt  = (len > 1) ? csr[base + 1] : s_cur;
            for (int j = 0; j < len; ++j) {
                int   s_n2  = (j + 2 < len) ? csr[base + j + 2] : s_nxt;
                float is_n  = isd[s_nxt];
                float xv_n  = x[(size_t)s_nxt * 64 + lane];
                float d0 = is_cur - mu0[0]; float g0 = __expf(d0 * d0 * w0[0] + e1[0]);
                float d1 = is_cur - mu0[1]; float g1 = __expf(d1 * d1 * w0[1] + e1[1]);
                float d2 = is_cur - mu0[2]; float g2 = __expf(d2 * d2 * w0[2] + e1[2]);
                float d3 = is_cur - mu0[3]; float g3 = __expf(d3 * d3 * w0[3] + e1[3]);
                a0 += g0 * xv_cur; a1 += g1 * xv_cur;
                a2 += g2 * xv_cur; a3 += g3 * xv_cur;
                is_cur = is_n; xv_cur = xv_n; s_nxt = s_n2;
            }
        }
        const float invd = 1.0f / (float)(len > 1 ? len : 1);
        size_t hb = (size_t)node * 256;
        h[hb + lane]        = a0 * invd;
        h[hb + 64 + lane]   = a1 * invd;
        h[hb + 128 + lane]  = a2 * invd;
        h[hb + 192 + lane]  = a3 * invd;
    }
}

// ---------- fused transform: out = x + relu(h@B + x@root + bias) ----------
// B[c][j] = g[c&63][(c>>6)*64 + j] staged in LDS (64 KB exactly).
// Wave tile = 16 rows; lane = output col j. h/x loads are lane-varying
// coalesced; the per-element h[r][c] broadcast uses v_readlane (VALU pipe).
__global__ __launch_bounds__(256, 2) void k_tx(const float* __restrict__ h,
                                               const float* __restrict__ x,
                                               const float* __restrict__ g,
                                               const float* __restrict__ root,
                                               const float* __restrict__ bias,
                                               float* __restrict__ out, int n) {
    __shared__ float Bs[256 * 64];
    for (int t = threadIdx.x; t < 4096; t += 256) {
        int idx = t * 4;
        int c = idx >> 6;
        int j = idx & 63;                  // multiple of 4
        int k = c >> 6, i = c & 63;
        *reinterpret_cast<float4*>(&Bs[idx]) =
            *reinterpret_cast<const float4*>(&g[i * 256 + k * 64 + j]);
    }
    __syncthreads();

    const int lane  = threadIdx.x & 63;
    const int w     = __builtin_amdgcn_readfirstlane(threadIdx.x >> 6);
    const int ntile = (n + 15) >> 4;
    const float bias_v = bias[lane];

    for (int tile = blockIdx.x * 4 + w; tile < ntile; tile += gridDim.x * 4) {
        const int r0 = tile * 16;
        float hvA[16], hvB[16], xv[16], acc[16];

        #pragma unroll
        for (int r = 0; r < 16; ++r) {
            int row = r0 + r; row = row < n ? row : n - 1;
            xv[r]  = x[(size_t)row * 64 + lane];
            hvA[r] = h[(size_t)row * 256 + lane];          // seg 0
            acc[r] = bias_v;
        }

        #pragma unroll
        for (int seg = 0; seg < 4; ++seg) {
            float (&cur)[16] = (seg & 1) ? hvB : hvA;
            float (&nxt)[16] = (seg & 1) ? hvA : hvB;
            if (seg < 3) {
                #pragma unroll
                for (int r = 0; r < 16; ++r) {
                    int row = r0 + r; row = row < n ? row : n - 1;
                    nxt[r] = h[(size_t)row * 256 + (seg + 1) * 64 + lane];
                }
            }
            const float* Brow = &Bs[seg * 64 * 64];
            for (int dd = 0; dd < 64; ++dd) {
                float bB = Brow[dd * 64 + lane];           // stride-1 over lanes
                #pragma unroll
                for (int r = 0; r < 16; ++r)
                    acc[r] = fmaf(rl(cur[r], dd), bB, acc[r]);
            }
        }

        // x @ root part: root row dd is 256B, 16KB total -> L1-resident
        for (int dd = 0; dd < 64; ++dd) {
            float rv = root[dd * 64 + lane];
            #pragma unroll
            for (int r = 0; r < 16; ++r)
                acc[r] = fmaf(rl(xv[r], dd), rv, acc[r]);
        }

        #pragma unroll
        for (int r = 0; r < 16; ++r) {
            int row = r0 + r;
            if (row < n) {
                float conv = acc[r];
                out[(size_t)row * 64 + lane] = xv[r] + (conv > 0.f ? conv : 0.f);
            }
        }
    }
}

extern "C" void kernel_launch(void* const* d_in, const int* in_sizes, int n_in,
                              void* d_out, int out_size, void* d_ws, size_t ws_size,
                              hipStream_t stream) {
    const float* x     = (const float*)d_in[0];
    const int*   ei    = (const int*)d_in[1];
    const float* g     = (const float*)d_in[2];
    const float* mu    = (const float*)d_in[3];
    const float* sigma = (const float*)d_in[4];
    const float* root  = (const float*)d_in[5];
    const float* bias  = (const float*)d_in[6];
    float* out = (float*)d_out;

    const int n = in_sizes[0] / 64;   // 100000
    const int E = in_sizes[1] / 2;    // 1600000
    const int nb = (n + 1023) / 1024; // scan blocks (98)

    // ws layout (4B units):
    //   counts[n] | off[n+4] | cursor[n] | isd[n] | bsum[128] | bpre[128] | csr[E] | h[n*256]
    // h offset = 4n+4+256+E floats -> 8,001,040 B (16B-aligned). Total ≈ 110.4 MB.
    int*   counts = (int*)d_ws;
    int*   off    = counts + n;
    int*   cursor = off + n + 4;
    float* isd    = (float*)(cursor + n);
    int*   bsum   = (int*)(isd + n);
    int*   bpre   = bsum + 128;
    int*   csr    = bpre + 128;
    float* h      = (float*)(csr + E);

    hipMemsetAsync(counts, 0, (size_t)n * sizeof(int), stream);

    k_hist<<<(E + 255) / 256, 256, 0, stream>>>(ei, E, counts);
    k_scan1<<<nb, 1024, 0, stream>>>(counts, n, bsum);
    k_scan2<<<1, 1024, 0, stream>>>(bsum, bpre, nb);
    k_scan3<<<nb, 1024, 0, stream>>>(counts, bpre, off, cursor, isd, n);
    k_fill<<<(E + 255) / 256, 256, 0, stream>>>(ei, E, cursor, csr);
    k_gather<<<2048, 256, 0, stream>>>(off, csr, isd, x, mu, sigma, h, n);
    k_tx<<<512, 256, 0, stream>>>(h, x, g, root, bias, out, n);
}